// Round 20
// baseline (281.026 us; speedup 1.0000x reference)
//
#include <hip/hip_runtime.h>
#include <hip/hip_bf16.h>
#include <math.h>

#define BB 32
#define CC 128
#define HH 56
#define WW 56
#define HWHW 3136
#define TOK 100352         // B*H*W
#define BH 1792            // B*H
#define NDP 576            // padded W*d (560 -> 576)
#define NNP 3200           // padded W*W (3136 -> 3200)

typedef __attribute__((ext_vector_type(8))) short bhalf8;
typedef __attribute__((ext_vector_type(4))) float f32x4;
typedef __attribute__((ext_vector_type(4))) unsigned int u32x4;

__device__ inline unsigned short f2bf(float f) {
  __bf16 h = (__bf16)f;               // compiler emits HW cvt (RNE) on gfx950
  unsigned short u;
  __builtin_memcpy(&u, &h, 2);
  return u;
}
__device__ inline float bf2f(unsigned short u) {
  return __uint_as_float(((unsigned int)u) << 16);
}
__device__ inline unsigned int pack2(float a, float b) {
  return (unsigned int)f2bf(a) | ((unsigned int)f2bf(b) << 16);
}
__device__ inline f32x4 MFMA(bhalf8 a, bhalf8 b, f32x4 c) {
  return __builtin_amdgcn_mfma_f32_16x16x32_bf16(a, b, c, 0, 0, 0);
}
// swizzled LDS frag read: tile [rows][CH*8] bf16, chunk XOR (row&7)
template <int CH>
__device__ inline bhalf8 ldsFrag(const unsigned short* base, int row, int chunk) {
  return *reinterpret_cast<const bhalf8*>(base + row * (CH * 8) + ((chunk ^ (row & 7)) * 8));
}
__device__ inline bhalf8 gFrag(const unsigned short* p) {
  return *reinterpret_cast<const bhalf8*>(p);
}
// gelu = x * e/(e+1), e = exp(2*0.79788456*(x + 0.044715 x^3)); fast rcp (1 ulp, fine for bf16)
__device__ inline float gelu_f(float x) {
  float x3 = x * x * x;
  float z2 = 1.5957691216057308f * (x + 0.044715f * x3);
  float e = __expf(z2);
  return x * e * __builtin_amdgcn_rcpf(e + 1.0f);
}

// ---------------- weights prep: tiled transpose-convert + (extra blocks) pad-zero/wcat ----------------
__global__ __launch_bounds__(256) void wtrans_kernel(
    const float* __restrict__ hwnn, const float* __restrict__ wwnn,
    const float* __restrict__ pcw, const float* __restrict__ pow_,
    const float* __restrict__ fc1w, const float* __restrict__ fc2w,
    const float* __restrict__ hwnd, const float* __restrict__ wwnd,
    unsigned short* __restrict__ wnnTh, unsigned short* __restrict__ wnnTw,
    unsigned short* __restrict__ pcT, unsigned short* __restrict__ poT,
    unsigned short* __restrict__ fc1T, unsigned short* __restrict__ fc2T,
    unsigned short* __restrict__ wcatT, u32x4* __restrict__ pdzero) {
  __shared__ unsigned short t[64][65];
  int bid = blockIdx.x;
  int tid = threadIdx.x;
  if (bid >= 940) {   // 64 tail blocks: zero pdh/pdw, build wcatT
    int gt = (bid - 940) * 256 + tid, gs = 64 * 256;
    for (int i = gt; i < 258048; i += gs) { u32x4 z = {0, 0, 0, 0}; pdzero[i] = z; }
    for (int i = gt; i < 128 * 32; i += gs) {
      int k = i >> 5, n = i & 31;
      float v = n < 10 ? hwnd[k * 10 + n] : (n < 20 ? wwnd[k * 10 + (n - 10)] : 0.f);
      wcatT[n * 128 + k] = f2bf(v);
    }
    return;
  }
  const float* src; unsigned short* dst;
  int K, N, Kp, Np, bx, by;
  if (bid < 450)      { src = hwnn; dst = wnnTh; K = 560; N = 3136; Kp = 576; Np = 3200; int b = bid;       bx = b % 50; by = b / 50; }
  else if (bid < 900) { src = wwnn; dst = wnnTw; K = 560; N = 3136; Kp = 576; Np = 3200; int b = bid - 450; bx = b % 50; by = b / 50; }
  else if (bid < 904) { src = pcw;  dst = pcT;   K = 128; N = 128;  Kp = 128; Np = 128;  int b = bid - 900; bx = b % 2;  by = b / 2; }
  else if (bid < 908) { src = pow_; dst = poT;   K = 128; N = 128;  Kp = 128; Np = 128;  int b = bid - 904; bx = b % 2;  by = b / 2; }
  else if (bid < 924) { src = fc1w; dst = fc1T;  K = 128; N = 512;  Kp = 128; Np = 512;  int b = bid - 908; bx = b % 8;  by = b / 8; }
  else                { src = fc2w; dst = fc2T;  K = 512; N = 128;  Kp = 512; Np = 128;  int b = bid - 924; bx = b % 2;  by = b / 2; }
  int n0 = bx * 64, k0 = by * 64;
  for (int idx = tid; idx < 4096; idx += 256) {
    int kk = idx >> 6, nn = idx & 63;
    float v = (k0 + kk < K && n0 + nn < N) ? src[(size_t)(k0 + kk) * N + n0 + nn] : 0.f;
    t[nn][kk] = f2bf(v);
  }
  __syncthreads();
  for (int idx = tid; idx < 4096; idx += 256) {
    int nn = idx >> 6, kk = idx & 63;
    if (n0 + nn < Np && k0 + kk < Kp)
      dst[(size_t)(n0 + nn) * Kp + k0 + kk] = t[nn][kk];
  }
}

// ---------------- LN1: x -> ubf (normal) + ubfT (transposed) + xcl (TRANSPOSED) ----------------
__global__ __launch_bounds__(256) void ln1_kernel(const float* __restrict__ x,
    const float* __restrict__ g, const float* __restrict__ bt,
    unsigned short* __restrict__ ubf, unsigned short* __restrict__ ubfT,
    unsigned short* __restrict__ xcl) {
  int bh = blockIdx.x;
  int b = bh / HH, h = bh % HH;
  __shared__ float lds[WW][CC + 1];
  __shared__ float mu[WW], rs[WW];
  const float* xp = x + ((size_t)b * CC) * HWHW + (size_t)h * WW;
  for (int idx = threadIdx.x; idx < CC * WW; idx += 256) {
    int c = idx / WW, w = idx % WW;
    lds[w][c] = xp[(size_t)c * HWHW + w];
  }
  __syncthreads();
  if (threadIdx.x < WW) {
    int w = threadIdx.x;
    float s = 0.f, ss = 0.f;
    for (int c = 0; c < CC; ++c) { float v = lds[w][c]; s += v; ss += v * v; }
    float m = s * (1.0f / CC);
    float var = ss * (1.0f / CC) - m * m;
    mu[w] = m; rs[w] = rsqrtf(var + 1e-5f);
  }
  __syncthreads();
  unsigned short* up = ubf + (size_t)bh * (WW * CC);
  size_t tbase = ((size_t)b * HWHW + h) * 128;
  for (int idx = threadIdx.x; idx < WW * CC; idx += 256) {
    int w = idx >> 7, c = idx & 127;
    float v = lds[w][c];
    float uv = (v - mu[w]) * rs[w] * g[c] + bt[c];
    unsigned short ub = f2bf(uv);
    up[idx] = ub;
    size_t ta = tbase + (size_t)w * (56 * 128) + c;   // [b][w][h][c]
    ubfT[ta] = ub;
    xcl[ta] = f2bf(v);
  }
}

// ---------------- pd (MFMA): per-token 128->20 projection, scatter to pdh/pdw ----------------
__global__ __launch_bounds__(256) void pd_mfma(const unsigned short* __restrict__ ubf,
    const unsigned short* __restrict__ wcatT, const float* __restrict__ hbnd,
    const float* __restrict__ wbnd, unsigned short* __restrict__ pdh,
    unsigned short* __restrict__ pdw) {
  __shared__ __align__(16) unsigned short sU[64 * 128];
  __shared__ __align__(16) unsigned short sW[32 * 128];
  int tid = threadIdx.x;
  int tok0 = blockIdx.x * 64;
  #pragma unroll
  for (int i = 0; i < 4; ++i) {
    int s = i * 256 + tid; int r = s >> 4, c = s & 15;
    u32x4 v = *reinterpret_cast<const u32x4*>(ubf + (size_t)(tok0 + r) * 128 + c * 8);
    *reinterpret_cast<u32x4*>(sU + r * 128 + ((c ^ (r & 7)) * 8)) = v;
  }
  #pragma unroll
  for (int i = 0; i < 2; ++i) {
    int s = i * 256 + tid; int r = s >> 4, c = s & 15;
    u32x4 v = *reinterpret_cast<const u32x4*>(wcatT + (size_t)r * 128 + c * 8);
    *reinterpret_cast<u32x4*>(sW + r * 128 + ((c ^ (r & 7)) * 8)) = v;
  }
  __syncthreads();
  int wid = tid >> 6, lane = tid & 63, l16 = lane & 15, lk = lane >> 4;
  f32x4 acc[2] = {};
  #pragma unroll
  for (int kk = 0; kk < 4; ++kk) {
    bhalf8 a = ldsFrag<16>(sU, wid * 16 + l16, kk * 4 + lk);
    #pragma unroll
    for (int f = 0; f < 2; ++f) {
      bhalf8 b = ldsFrag<16>(sW, f * 16 + l16, kk * 4 + lk);
      acc[f] = MFMA(a, b, acc[f]);
    }
  }
  #pragma unroll
  for (int f = 0; f < 2; ++f) {
    int n = f * 16 + l16;
    #pragma unroll
    for (int r = 0; r < 4; ++r) {
      int tok = tok0 + wid * 16 + lk * 4 + r;
      float v = acc[f][r];
      if (n < 10) {
        pdh[((size_t)(tok / 56)) * NDP + (size_t)(tok % 56) * 10 + n] = f2bf(v + hbnd[n]);
      } else if (n < 20) {
        int b = tok / HWHW; int rem = tok % HWHW; int hh = rem / 56; int w = rem % 56;
        pdw[((size_t)(b * 56 + w)) * NDP + (size_t)hh * 10 + (n - 10)] = f2bf(v + wbnd[n - 10]);
      }
    }
  }
}

// ---------------- merged logits GEMM: both h- and w-direction in one launch ----------------
__global__ __launch_bounds__(256) void gemm_logits(
    const unsigned short* __restrict__ pdh, const unsigned short* __restrict__ pdw,
    const unsigned short* __restrict__ wnnTh, const unsigned short* __restrict__ wnnTw,
    const float* __restrict__ hbnn, const float* __restrict__ wbnn,
    unsigned short* __restrict__ ph, unsigned short* __restrict__ pwb) {
  __shared__ __align__(16) unsigned short sA[128 * 64];
  __shared__ __align__(16) unsigned short sB[128 * 64];
  int tid = threadIdx.x;
  int byr = blockIdx.y;
  const unsigned short* A; const unsigned short* BT; const float* bias; unsigned short* Cout;
  int row0;
  if (byr < 14) { A = pdh; BT = wnnTh; bias = hbnn; Cout = ph;  row0 = byr * 128; }
  else          { A = pdw; BT = wnnTw; bias = wbnn; Cout = pwb; row0 = (byr - 14) * 128; }
  int col0 = blockIdx.x * 128;
  int wid = tid >> 6, lane = tid & 63;
  int wm = wid >> 1, wn = wid & 1;
  int l16 = lane & 15, lk = lane >> 4;
  f32x4 acc[4][4] = {};
  for (int k0 = 0; k0 < NDP; k0 += 64) {
    #pragma unroll
    for (int i = 0; i < 4; ++i) {
      int s = i * 256 + tid; int r = s >> 3, c = s & 7;
      u32x4 v = *reinterpret_cast<const u32x4*>(A + (size_t)(row0 + r) * NDP + k0 + c * 8);
      *reinterpret_cast<u32x4*>(sA + r * 64 + ((c ^ (r & 7)) * 8)) = v;
    }
    #pragma unroll
    for (int i = 0; i < 4; ++i) {
      int s = i * 256 + tid; int r = s >> 3, c = s & 7;
      u32x4 v = *reinterpret_cast<const u32x4*>(BT + (size_t)(col0 + r) * NDP + k0 + c * 8);
      *reinterpret_cast<u32x4*>(sB + r * 64 + ((c ^ (r & 7)) * 8)) = v;
    }
    __syncthreads();
    bhalf8 af[4][2], bf[4][2];
    #pragma unroll
    for (int f = 0; f < 4; ++f)
      #pragma unroll
      for (int kk = 0; kk < 2; ++kk) {
        af[f][kk] = ldsFrag<8>(sA, wm * 64 + f * 16 + l16, kk * 4 + lk);
        bf[f][kk] = ldsFrag<8>(sB, wn * 64 + f * 16 + l16, kk * 4 + lk);
      }
    #pragma unroll
    for (int i = 0; i < 4; ++i)
      #pragma unroll
      for (int j = 0; j < 4; ++j) {
        acc[i][j] = MFMA(af[i][0], bf[j][0], acc[i][j]);
        acc[i][j] = MFMA(af[i][1], bf[j][1], acc[i][j]);
      }
    __syncthreads();
  }
  #pragma unroll
  for (int i = 0; i < 4; ++i) {
    int rbase = row0 + wm * 64 + i * 16 + lk * 4;
    #pragma unroll
    for (int j = 0; j < 4; ++j) {
      int col = col0 + wn * 64 + j * 16 + l16;
      if (col < HWHW) {
        float bv = bias[col];
        #pragma unroll
        for (int r = 0; r < 4; ++r)
          Cout[(size_t)(rbase + r) * NNP + col] = f2bf(acc[i][j][r] + bv);
      }
    }
  }
}

// ---------------- softmax over contiguous groups of 56 (bf16, row stride 3200) ----------------
__global__ __launch_bounds__(256) void softmax56_kernel(unsigned short* __restrict__ ph,
                                                        unsigned short* __restrict__ pw) {
  int wave = (blockIdx.x * 256 + threadIdx.x) >> 6;
  int lane = threadIdx.x & 63;
  if (wave >= 2 * TOK) return;
  unsigned short* buf = wave < TOK ? ph : pw;
  int row = wave < TOK ? wave : wave - TOK;
  int bh = row / 56, i = row % 56;
  unsigned short* p = buf + (size_t)bh * NNP + (size_t)i * 56;
  float xv = lane < WW ? bf2f(p[lane]) : -INFINITY;
  float m = xv;
  for (int o = 32; o > 0; o >>= 1) m = fmaxf(m, __shfl_xor(m, o));
  float e = lane < WW ? __expf(xv - m) : 0.f;
  float s = e;
  for (int o = 32; o > 0; o >>= 1) s += __shfl_xor(s, o);
  if (lane < WW) p[lane] = f2bf(e * __builtin_amdgcn_rcpf(s));
}

// ---------------- mix_h + pc fused: accmT = P_h @ U + U @ pc + pc_b  (transposed out) ----------------
__global__ __launch_bounds__(256) void mixh_pc(const unsigned short* __restrict__ ph,
    const unsigned short* __restrict__ ubf, const unsigned short* __restrict__ pcT,
    const float* __restrict__ pcb, unsigned short* __restrict__ accmT) {
  int bh = blockIdx.x;
  int b = bh / HH, h = bh % HH;
  int tok0 = bh * 56;
  __shared__ __align__(16) unsigned short sUt[128 * 64];
  int tid = threadIdx.x;
  for (int s = tid; s < 1024; s += 256) {
    int j = s >> 4, cc = s & 15;
    unsigned short e8[8] = {0, 0, 0, 0, 0, 0, 0, 0};
    if (j < 56)
      *reinterpret_cast<u32x4*>(e8) =
          *reinterpret_cast<const u32x4*>(ubf + (size_t)(tok0 + j) * 128 + cc * 8);
    #pragma unroll
    for (int e = 0; e < 8; ++e) {
      int cf = cc * 8 + e;
      sUt[cf * 64 + (((j >> 3) ^ (cf & 7)) * 8) + (j & 7)] = e8[e];
    }
  }
  __syncthreads();
  int lane = tid & 63, l16 = lane & 15, lk = lane >> 4, wn = tid >> 6;
  const unsigned short* prow = ph + (size_t)bh * NNP;
  f32x4 acc[4][2] = {};
  #pragma unroll
  for (int kk = 0; kk < 2; ++kk) {
    bhalf8 a[4], b[2];
    #pragma unroll
    for (int i = 0; i < 4; ++i)
      a[i] = gFrag(prow + (i * 16 + l16) * 56 + (kk * 4 + lk) * 8);
    #pragma unroll
    for (int j = 0; j < 2; ++j) b[j] = ldsFrag<8>(sUt, wn * 32 + j * 16 + l16, kk * 4 + lk);
    #pragma unroll
    for (int i = 0; i < 4; ++i)
      #pragma unroll
      for (int j = 0; j < 2; ++j) acc[i][j] = MFMA(a[i], b[j], acc[i][j]);
  }
  #pragma unroll
  for (int kk = 0; kk < 4; ++kk) {
    bhalf8 a[4], b[2];
    #pragma unroll
    for (int i = 0; i < 4; ++i)
      a[i] = gFrag(ubf + (size_t)(tok0 + i * 16 + l16) * 128 + (kk * 4 + lk) * 8);
    #pragma unroll
    for (int j = 0; j < 2; ++j)
      b[j] = gFrag(pcT + (size_t)(wn * 32 + j * 16 + l16) * 128 + (kk * 4 + lk) * 8);
    #pragma unroll
    for (int i = 0; i < 4; ++i)
      #pragma unroll
      for (int j = 0; j < 2; ++j) acc[i][j] = MFMA(a[i], b[j], acc[i][j]);
  }
  // write transposed: accmT[b][w][h][c], w = tok index within row
  #pragma unroll
  for (int i = 0; i < 4; ++i) {
    int tok = i * 16 + lk * 4;
    #pragma unroll
    for (int j = 0; j < 2; ++j) {
      int c = wn * 32 + j * 16 + l16;
      float bv = pcb[c];
      #pragma unroll
      for (int r = 0; r < 4; ++r)
        if (tok + r < 56)
          accmT[((size_t)b * HWHW + (size_t)(tok + r) * 56 + h) * 128 + c] =
              f2bf(acc[i][j][r] + bv);
    }
  }
}

// ---------------- mix_w + po + residual + LN2 fused (contiguous-slab inputs) ----------------
__global__ __launch_bounds__(256) void mixw_fin(const unsigned short* __restrict__ pw,
    const unsigned short* __restrict__ ubfT, const unsigned short* __restrict__ poT,
    const float* __restrict__ pob, const unsigned short* __restrict__ xclT,
    const unsigned short* __restrict__ accmT, unsigned short* __restrict__ accXt,
    const float* __restrict__ ln2g, const float* __restrict__ ln2b,
    unsigned short* __restrict__ vbf) {
  int bw = blockIdx.x;
  int bq = bw / 56, w = bw % 56;
  __shared__ __align__(16) unsigned short sUt[128 * 64];
  __shared__ __align__(16) unsigned short sS[64 * 128];
  __shared__ __align__(16) unsigned short xtile[56 * 128];
  int tid = threadIdx.x;
  size_t slab = ((size_t)bq * HWHW + (size_t)w * 56) * 128;   // 56 rows x 128 c
  const unsigned short* uslab = ubfT + slab;
  const unsigned short* aslab = accmT + slab;
  const unsigned short* xslab = xclT + slab;
  // contiguous slab loads
  for (int s = tid; s < 1024; s += 256) {
    int j = s >> 4, cc = s & 15;
    unsigned short e8[8] = {0, 0, 0, 0, 0, 0, 0, 0};
    if (j < 56)
      *reinterpret_cast<u32x4*>(e8) = *reinterpret_cast<const u32x4*>(uslab + j * 128 + cc * 8);
    #pragma unroll
    for (int e = 0; e < 8; ++e) {
      int cf = cc * 8 + e;
      sUt[cf * 64 + (((j >> 3) ^ (cf & 7)) * 8) + (j & 7)] = e8[e];
    }
  }
  for (int s = tid; s < 1024; s += 256) {
    int r = s >> 4, c = s & 15;
    u32x4 v = {0, 0, 0, 0};
    if (r < 56) v = *reinterpret_cast<const u32x4*>(aslab + r * 128 + c * 8);
    *reinterpret_cast<u32x4*>(sS + r * 128 + ((c ^ (r & 7)) * 8)) = v;
  }
  for (int s = tid; s < 896; s += 256)
    *reinterpret_cast<u32x4*>(xtile + s * 8) = *reinterpret_cast<const u32x4*>(xslab + s * 8);
  __syncthreads();
  int lane = tid & 63, l16 = lane & 15, lk = lane >> 4, wn = tid >> 6;
  const unsigned short* prow = pw + (size_t)bw * NNP;
  f32x4 acc1[4][2] = {};
  #pragma unroll
  for (int kk = 0; kk < 2; ++kk) {
    bhalf8 a[4], b[2];
    #pragma unroll
    for (int i = 0; i < 4; ++i)
      a[i] = gFrag(prow + (i * 16 + l16) * 56 + (kk * 4 + lk) * 8);
    #pragma unroll
    for (int j = 0; j < 2; ++j) b[j] = ldsFrag<8>(sUt, wn * 32 + j * 16 + l16, kk * 4 + lk);
    #pragma unroll
    for (int i = 0; i < 4; ++i)
      #pragma unroll
      for (int j = 0; j < 2; ++j) acc1[i][j] = MFMA(a[i], b[j], acc1[i][j]);
  }
  __syncthreads();
  // sS = accm_tile + yw  (RMW by owner lanes; pad rows stay zero)
  #pragma unroll
  for (int i = 0; i < 4; ++i) {
    #pragma unroll
    for (int j = 0; j < 2; ++j) {
      int col = wn * 32 + j * 16 + l16;
      #pragma unroll
      for (int r = 0; r < 4; ++r) {
        int row = i * 16 + lk * 4 + r;
        int ad = row * 128 + (((col >> 3) ^ (row & 7)) * 8) + (col & 7);
        sS[ad] = f2bf(bf2f(sS[ad]) + acc1[i][j][r]);
      }
    }
  }
  __syncthreads();
  f32x4 acc2[4][2] = {};
  #pragma unroll
  for (int kk = 0; kk < 4; ++kk) {
    bhalf8 a[4], b[2];
    #pragma unroll
    for (int i = 0; i < 4; ++i) a[i] = ldsFrag<16>(sS, i * 16 + l16, kk * 4 + lk);
    #pragma unroll
    for (int j = 0; j < 2; ++j)
      b[j] = gFrag(poT + (size_t)(wn * 32 + j * 16 + l16) * 128 + (kk * 4 + lk) * 8);
    #pragma unroll
    for (int i = 0; i < 4; ++i)
      #pragma unroll
      for (int j = 0; j < 2; ++j) acc2[i][j] = MFMA(a[i], b[j], acc2[i][j]);
  }
  __syncthreads();   // all A-frag reads of sS done before overwrite below
  #pragma unroll
  for (int i = 0; i < 4; ++i) {
    #pragma unroll
    for (int j = 0; j < 2; ++j) {
      int c = wn * 32 + j * 16 + l16;
      float bv = pob[c];
      #pragma unroll
      for (int r = 0; r < 4; ++r) {
        int row = i * 16 + lk * 4 + r;
        if (row < 56) {
          size_t t = (size_t)bq * HWHW + (size_t)row * 56 + w;
          float z = acc2[i][j][r] + bv + bf2f(xtile[row * 128 + c]);
          unsigned short zb = f2bf(z);
          accXt[t * 128 + c] = zb;
          sS[row * 128 + (((c >> 3) ^ (row & 7)) * 8) + (c & 7)] = zb;  // for LN phase
        }
      }
    }
  }
  __syncthreads();
  // LN2 phase: wave per row (56 rows), 2 channels per lane
  {
    int wid4 = tid >> 6;
    int c0 = 2 * lane;
    float g0 = ln2g[c0], g1 = ln2g[c0 + 1];
    float b0 = ln2b[c0], b1 = ln2b[c0 + 1];
    for (int row = wid4; row < 56; row += 4) {
      int ad = row * 128 + (((c0 >> 3) ^ (row & 7)) * 8) + (c0 & 7);
      unsigned int wrd = *reinterpret_cast<const unsigned int*>(sS + ad);
      float z0 = bf2f((unsigned short)(wrd & 0xFFFFu));
      float z1 = bf2f((unsigned short)(wrd >> 16));
      float s1 = z0 + z1, s2 = z0 * z0 + z1 * z1;
      for (int o = 32; o > 0; o >>= 1) { s1 += __shfl_xor(s1, o); s2 += __shfl_xor(s2, o); }
      float m = s1 * (1.0f / CC);
      float var = s2 * (1.0f / CC) - m * m;
      float rv = rsqrtf(var + 1e-5f);
      float n0 = (z0 - m) * rv * g0 + b0;
      float n1 = (z1 - m) * rv * g1 + b1;
      size_t t = (size_t)bq * HWHW + (size_t)row * 56 + w;
      *reinterpret_cast<unsigned int*>(vbf + t * 128 + c0) = pack2(n0, n1);
    }
  }
}

// ---------------- fc1 GEMM: h[tok][hid] = gelu(vbf @ fc1 + b1), K=128 ----------------
// XCD-chunked 1D grid: 3136 = 8 XCD x 98 tok-chunks x 4 hid
__global__ __launch_bounds__(256) void gemm_fc1(const unsigned short* __restrict__ vbf,
    const unsigned short* __restrict__ fc1T, const float* __restrict__ b1,
    unsigned short* __restrict__ hbuf) {
  __shared__ __align__(16) unsigned short sW[128 * 64];
  __shared__ __align__(16) unsigned short sV[128 * 64];
  __shared__ float b1s[128];
  int tid = threadIdx.x;
  int id = blockIdx.x;
  int xcd = id & 7, sub = id >> 3;
  int tok0 = (xcd * 98 + (sub >> 2)) * 128;
  int hidT = (sub & 3) * 128;
  if (tid < 128) b1s[tid] = b1[hidT + tid];
  int wid = tid >> 6, lane = tid & 63;
  int wm = wid >> 1, wn = wid & 1;      // wm: hid half, wn: tok half
  int l16 = lane & 15, lk = lane >> 4;
  f32x4 acc[4][4] = {};
  for (int k0 = 0; k0 < 128; k0 += 64) {
    #pragma unroll
    for (int i = 0; i < 4; ++i) {
      int s = i * 256 + tid; int r = s >> 3, c = s & 7;
      u32x4 v = *reinterpret_cast<const u32x4*>(fc1T + (size_t)(hidT + r) * 128 + k0 + c * 8);
      *reinterpret_cast<u32x4*>(sW + r * 64 + ((c ^ (r & 7)) * 8)) = v;
    }
    #pragma unroll
    for (int i = 0; i < 4; ++i) {
      int s = i * 256 + tid; int r = s >> 3, c = s & 7;
      u32x4 v = *reinterpret_cast<const u32x4*>(vbf + (size_t)(tok0 + r) * 128 + k0 + c * 8);
      *reinterpret_cast<u32x4*>(sV + r * 64 + ((c ^ (r & 7)) * 8)) = v;
    }
    __syncthreads();
    bhalf8 af[4][2], bf[4][2];
    #pragma unroll
    for (int f = 0; f < 4; ++f)
      #pragma unroll
      for (int kk = 0; kk < 2; ++kk) {
        af[f][kk] = ldsFrag<8>(sW, wm * 64 + f * 16 + l16, kk * 4 + lk);
        bf[f][kk] = ldsFrag<8>(sV, wn * 64 + f * 16 + l16, kk * 4 + lk);
      }
    #pragma unroll
    for (int i = 0; i < 4; ++i)
      #pragma unroll
      for (int j = 0; j < 4; ++j) {
        acc[i][j] = MFMA(af[i][0], bf[j][0], acc[i][j]);
        acc[i][j] = MFMA(af[i][1], bf[j][1], acc[i][j]);
      }
    __syncthreads();
  }
  #pragma unroll
  for (int i = 0; i < 4; ++i) {
    int hidL = wm * 64 + i * 16 + lk * 4;
    #pragma unroll
    for (int j = 0; j < 4; ++j) {
      int tokL = wn * 64 + j * 16 + l16;
      float v0 = gelu_f(acc[i][j][0] + b1s[hidL]);
      float v1 = gelu_f(acc[i][j][1] + b1s[hidL + 1]);
      float v2 = gelu_f(acc[i][j][2] + b1s[hidL + 2]);
      float v3 = gelu_f(acc[i][j][3] + b1s[hidL + 3]);
      unsigned long long pk = (unsigned long long)pack2(v0, v1)
                            | ((unsigned long long)pack2(v2, v3) << 32);
      *reinterpret_cast<unsigned long long*>(
          hbuf + (size_t)(tok0 + tokL) * 512 + hidT + hidL) = pk;
    }
  }
}

// ---------------- fc2 GEMM: out = T(xt2 + h @ fc2 + b2), K=512 ----------------
__global__ __launch_bounds__(256) void gemm_fc2(const unsigned short* __restrict__ hbuf,
    const unsigned short* __restrict__ fc2T, const float* __restrict__ b2,
    const unsigned short* __restrict__ xt2, float* __restrict__ out) {
  __shared__ __align__(16) unsigned short smem[2][128 * 64];   // sH / sC, reused as xtile
  __shared__ float b2s[128];
  unsigned short* sH = smem[0];
  unsigned short* sC = smem[1];
  unsigned short* xtile = &smem[0][0];   // 128x128 bf16 = 32KB (both halves)
  int tid = threadIdx.x;
  int tok0 = blockIdx.x * 128;
  if (tid < 128) b2s[tid] = b2[tid];
  int wid = tid >> 6, lane = tid & 63;
  int wm = wid >> 1, wn = wid & 1;       // wm: tok half, wn: c half
  int l16 = lane & 15, lk = lane >> 4;
  f32x4 acc[4][4] = {};
  for (int k0 = 0; k0 < 512; k0 += 64) {
    #pragma unroll
    for (int i = 0; i < 4; ++i) {
      int s = i * 256 + tid; int r = s >> 3, c = s & 7;
      u32x4 v = *reinterpret_cast<const u32x4*>(hbuf + (size_t)(tok0 + r) * 512 + k0 + c * 8);
      *reinterpret_cast<u32x4*>(sH + r * 64 + ((c ^ (r & 7)) * 8)) = v;
    }
    #pragma unroll
    for (int i = 0; i < 4; ++i) {
      int s = i * 256 + tid; int r = s >> 3, c = s & 7;
      u32x4 v = *reinterpret_cast<const u32x4*>(fc2T + (size_t)r * 512 + k0 + c * 8);
      *reinterpret_cast<u32x4*>(sC + r * 64 + ((c ^ (r & 7)) * 8)) = v;
    }
    __syncthreads();
    bhalf8 af[4][2], bf[4][2];
    #pragma unroll
    for (int f = 0; f < 4; ++f)
      #pragma unroll
      for (int kk = 0; kk < 2; ++kk) {
        af[f][kk] = ldsFrag<8>(sH, wm * 64 + f * 16 + l16, kk * 4 + lk);
        bf[f][kk] = ldsFrag<8>(sC, wn * 64 + f * 16 + l16, kk * 4 + lk);
      }
    #pragma unroll
    for (int i = 0; i < 4; ++i)
      #pragma unroll
      for (int j = 0; j < 4; ++j) {
        acc[i][j] = MFMA(af[i][0], bf[j][0], acc[i][j]);
        acc[i][j] = MFMA(af[i][1], bf[j][1], acc[i][j]);
      }
    __syncthreads();
  }
  // stage xt2 tile [128 tok][128 c] into LDS (linear), then epilogue
  #pragma unroll
  for (int i = 0; i < 8; ++i) {
    int s = i * 256 + tid; int r = s >> 4, c = s & 15;
    u32x4 v = *reinterpret_cast<const u32x4*>(xt2 + (size_t)(tok0 + r) * 128 + c * 8);
    *reinterpret_cast<u32x4*>(xtile + r * 128 + c * 8) = v;
  }
  __syncthreads();
  #pragma unroll
  for (int i = 0; i < 4; ++i) {
    int tokL = wm * 64 + i * 16 + lk * 4;
    int tokG = tok0 + tokL;
    int bqv = tokG / HWHW;
    int pos = tokG - bqv * HWHW;
    #pragma unroll
    for (int j = 0; j < 4; ++j) {
      int cL = wn * 64 + j * 16 + l16;
      float bv = b2s[cL];
      f32x4 o;
      #pragma unroll
      for (int r = 0; r < 4; ++r)
        o[r] = acc[i][j][r] + bv + bf2f(xtile[(tokL + r) * 128 + cL]);
      *reinterpret_cast<f32x4*>(out + ((size_t)(bqv * CC + cL)) * HWHW + pos) = o;
    }
  }
}

extern "C" void kernel_launch(void* const* d_in, const int* in_sizes, int n_in,
                              void* d_out, int out_size, void* d_ws, size_t ws_size,
                              hipStream_t stream) {
  const float* x     = (const float*)d_in[0];
  const float* ln1_g = (const float*)d_in[1];
  const float* ln1_b = (const float*)d_in[2];
  const float* h_wnd = (const float*)d_in[3];
  const float* h_bnd = (const float*)d_in[4];
  const float* h_wnn = (const float*)d_in[5];
  const float* h_bnn = (const float*)d_in[6];
  const float* w_wnd = (const float*)d_in[7];
  const float* w_bnd = (const float*)d_in[8];
  const float* w_wnn = (const float*)d_in[9];
  const float* w_bnn = (const float*)d_in[10];
  const float* pc_w  = (const float*)d_in[11];
  const float* pc_b  = (const float*)d_in[12];
  const float* po_w  = (const float*)d_in[13];
  const float* po_b  = (const float*)d_in[14];
  const float* ln2_g = (const float*)d_in[15];
  const float* ln2_b = (const float*)d_in[16];
  const float* fc1_w = (const float*)d_in[17];
  const float* fc1_b = (const float*)d_in[18];
  const float* fc2_w = (const float*)d_in[19];
  const float* fc2_b = (const float*)d_in[20];
  float* out = (float*)d_out;
  char* ws = (char*)d_ws;

  // ---- workspace layout (bytes), total ~231.5 MB (ws = 256 MiB) ----
  unsigned short* ubf   = (unsigned short*)(ws + 0);            // 25,690,112 (u normal; later vbf)
  unsigned short* xclT  = (unsigned short*)(ws + 25690112);     // 25,690,112 (x, TRANSPOSED [b][w][h][c])
  unsigned short* accXt = (unsigned short*)(ws + 51380224);     // 25,690,112 (xt2, normal order)
  // region 77,070,336..179,830,784: early buffers; later hbuf (102,760,448)
  unsigned short* pdh   = (unsigned short*)(ws + 77070336);     //  2,064,384
  unsigned short* pdw   = (unsigned short*)(ws + 79134720);     //  2,064,384
  unsigned short* ph    = (unsigned short*)(ws + 81199104);     // 11,468,800
  unsigned short* pw    = (unsigned short*)(ws + 92667904);     // 11,468,800
  unsigned short* wnnTh = (unsigned short*)(ws + 104136704);    //  3,686,400
  unsigned short* wnnTw = (unsigned short*)(ws + 107823104);    //  3,686,400
  unsigned short* hbuf  = (unsigned short*)(ws + 77070336);     // 102,760,448 (after mixes)
  unsigned short* pcT   = (unsigned short*)(ws + 179830784);    //     32,768
  unsigned short* poT   = (unsigned short*)(ws + 179863552);    //     32,768
  unsigned short* fc1T  = (unsigned short*)(ws + 179896320);    //    131,072
  unsigned short* fc2T  = (unsigned short*)(ws + 180027392);    //    131,072
  unsigned short* wcatT = (unsigned short*)(ws + 180158464);    //      8,192
  unsigned short* ubfT  = (unsigned short*)(ws + 180166656);    // 25,690,112 (u, TRANSPOSED)
  unsigned short* accmT = (unsigned short*)(ws + 205856768);    // 25,690,112 (accm, TRANSPOSED) -> 231,546,880
  unsigned short* vbf   = ubf;                                  // reuse (ubf dead after fc1? no: after mixh/pd; mixw writes vbf, reads ubfT)

  wtrans_kernel<<<1004, 256, 0, stream>>>(h_wnn, w_wnn, pc_w, po_w, fc1_w, fc2_w,
      h_wnd, w_wnd, wnnTh, wnnTw, pcT, poT, fc1T, fc2T, wcatT, (u32x4*)pdh);
  ln1_kernel<<<BH, 256, 0, stream>>>(x, ln1_g, ln1_b, ubf, ubfT, xclT);
  pd_mfma<<<TOK / 64, 256, 0, stream>>>(ubf, wcatT, h_bnd, w_bnd, pdh, pdw);
  gemm_logits<<<dim3(NNP / 128, 28), 256, 0, stream>>>(pdh, pdw, wnnTh, wnnTw,
      h_bnn, w_bnn, ph, pw);
  softmax56_kernel<<<(2 * TOK) / 4, 256, 0, stream>>>(ph, pw);
  mixh_pc<<<BH, 256, 0, stream>>>(ph, ubf, pcT, pc_b, accmT);
  mixw_fin<<<BB * WW, 256, 0, stream>>>(pw, ubfT, poT, po_b, xclT, accmT, accXt,
      ln2_g, ln2_b, vbf);
  gemm_fc1<<<3136, 256, 0, stream>>>(vbf, fc1T, fc1_b, hbuf);
  gemm_fc2<<<TOK / 128, 256, 0, stream>>>(hbuf, fc2T, fc2_b, accXt, out);
}

// Round 21
// 268.461 us; speedup vs baseline: 1.0468x; 1.0468x over previous
//
#include <hip/hip_runtime.h>
#include <hip/hip_bf16.h>
#include <math.h>

#define BB 32
#define CC 128
#define HH 56
#define WW 56
#define HWHW 3136
#define TOK 100352         // B*H*W
#define BH 1792            // B*H
#define NDP 576            // padded W*d (560 -> 576)
#define NNP 3200           // padded W*W (3136 -> 3200)

typedef __attribute__((ext_vector_type(8))) short bhalf8;
typedef __attribute__((ext_vector_type(4))) float f32x4;
typedef __attribute__((ext_vector_type(4))) unsigned int u32x4;

__device__ inline unsigned short f2bf(float f) {
  __bf16 h = (__bf16)f;               // compiler emits HW cvt (RNE) on gfx950
  unsigned short u;
  __builtin_memcpy(&u, &h, 2);
  return u;
}
__device__ inline float bf2f(unsigned short u) {
  return __uint_as_float(((unsigned int)u) << 16);
}
__device__ inline unsigned int pack2(float a, float b) {
  return (unsigned int)f2bf(a) | ((unsigned int)f2bf(b) << 16);
}
__device__ inline f32x4 MFMA(bhalf8 a, bhalf8 b, f32x4 c) {
  return __builtin_amdgcn_mfma_f32_16x16x32_bf16(a, b, c, 0, 0, 0);
}
// swizzled LDS frag read: tile [rows][CH*8] bf16, chunk XOR (row&7)
template <int CH>
__device__ inline bhalf8 ldsFrag(const unsigned short* base, int row, int chunk) {
  return *reinterpret_cast<const bhalf8*>(base + row * (CH * 8) + ((chunk ^ (row & 7)) * 8));
}
__device__ inline bhalf8 gFrag(const unsigned short* p) {
  return *reinterpret_cast<const bhalf8*>(p);
}
// gelu = x * e/(e+1), e = exp(2*0.79788456*(x + 0.044715 x^3)); fast rcp (1 ulp, fine for bf16)
__device__ inline float gelu_f(float x) {
  float x3 = x * x * x;
  float z2 = 1.5957691216057308f * (x + 0.044715f * x3);
  float e = __expf(z2);
  return x * e * __builtin_amdgcn_rcpf(e + 1.0f);
}

// ---------------- weights prep: tiled transpose-convert + (extra blocks) pad-zero/wcat ----------------
__global__ __launch_bounds__(256) void wtrans_kernel(
    const float* __restrict__ hwnn, const float* __restrict__ wwnn,
    const float* __restrict__ pcw, const float* __restrict__ pow_,
    const float* __restrict__ fc1w, const float* __restrict__ fc2w,
    const float* __restrict__ hwnd, const float* __restrict__ wwnd,
    unsigned short* __restrict__ wnnTh, unsigned short* __restrict__ wnnTw,
    unsigned short* __restrict__ pcT, unsigned short* __restrict__ poT,
    unsigned short* __restrict__ fc1T, unsigned short* __restrict__ fc2T,
    unsigned short* __restrict__ wcatT, u32x4* __restrict__ pdzero) {
  __shared__ unsigned short t[64][65];
  int bid = blockIdx.x;
  int tid = threadIdx.x;
  if (bid >= 940) {   // 64 tail blocks: zero pdh/pdw, build wcatT
    int gt = (bid - 940) * 256 + tid, gs = 64 * 256;
    for (int i = gt; i < 258048; i += gs) { u32x4 z = {0, 0, 0, 0}; pdzero[i] = z; }
    for (int i = gt; i < 128 * 32; i += gs) {
      int k = i >> 5, n = i & 31;
      float v = n < 10 ? hwnd[k * 10 + n] : (n < 20 ? wwnd[k * 10 + (n - 10)] : 0.f);
      wcatT[n * 128 + k] = f2bf(v);
    }
    return;
  }
  const float* src; unsigned short* dst;
  int K, N, Kp, Np, bx, by;
  if (bid < 450)      { src = hwnn; dst = wnnTh; K = 560; N = 3136; Kp = 576; Np = 3200; int b = bid;       bx = b % 50; by = b / 50; }
  else if (bid < 900) { src = wwnn; dst = wnnTw; K = 560; N = 3136; Kp = 576; Np = 3200; int b = bid - 450; bx = b % 50; by = b / 50; }
  else if (bid < 904) { src = pcw;  dst = pcT;   K = 128; N = 128;  Kp = 128; Np = 128;  int b = bid - 900; bx = b % 2;  by = b / 2; }
  else if (bid < 908) { src = pow_; dst = poT;   K = 128; N = 128;  Kp = 128; Np = 128;  int b = bid - 904; bx = b % 2;  by = b / 2; }
  else if (bid < 924) { src = fc1w; dst = fc1T;  K = 128; N = 512;  Kp = 128; Np = 512;  int b = bid - 908; bx = b % 8;  by = b / 8; }
  else                { src = fc2w; dst = fc2T;  K = 512; N = 128;  Kp = 512; Np = 128;  int b = bid - 924; bx = b % 2;  by = b / 2; }
  int n0 = bx * 64, k0 = by * 64;
  for (int idx = tid; idx < 4096; idx += 256) {
    int kk = idx >> 6, nn = idx & 63;
    float v = (k0 + kk < K && n0 + nn < N) ? src[(size_t)(k0 + kk) * N + n0 + nn] : 0.f;
    t[nn][kk] = f2bf(v);
  }
  __syncthreads();
  for (int idx = tid; idx < 4096; idx += 256) {
    int nn = idx >> 6, kk = idx & 63;
    if (n0 + nn < Np && k0 + kk < Kp)
      dst[(size_t)(n0 + nn) * Kp + k0 + kk] = t[nn][kk];
  }
}

// ---------------- LN1: x[B,C,H,W] -> ubf[B,H,W,C] bf16 + xcl[B,H,W,C] bf16 ----------------
__global__ __launch_bounds__(256) void ln1_kernel(const float* __restrict__ x,
    const float* __restrict__ g, const float* __restrict__ bt,
    unsigned short* __restrict__ ubf, unsigned short* __restrict__ xcl) {
  int bh = blockIdx.x;
  int b = bh / HH, h = bh % HH;
  __shared__ float lds[WW][CC + 1];
  __shared__ float mu[WW], rs[WW];
  const float* xp = x + ((size_t)b * CC) * HWHW + (size_t)h * WW;
  for (int idx = threadIdx.x; idx < CC * WW; idx += 256) {
    int c = idx / WW, w = idx % WW;
    lds[w][c] = xp[(size_t)c * HWHW + w];
  }
  __syncthreads();
  if (threadIdx.x < WW) {
    int w = threadIdx.x;
    float s = 0.f, ss = 0.f;
    for (int c = 0; c < CC; ++c) { float v = lds[w][c]; s += v; ss += v * v; }
    float m = s * (1.0f / CC);
    float var = ss * (1.0f / CC) - m * m;
    mu[w] = m; rs[w] = rsqrtf(var + 1e-5f);
  }
  __syncthreads();
  unsigned short* up = ubf + (size_t)bh * (WW * CC);
  unsigned short* xc = xcl + (size_t)bh * (WW * CC);
  for (int idx = threadIdx.x; idx < WW * CC; idx += 256) {
    int w = idx >> 7, c = idx & 127;
    float v = lds[w][c];
    up[idx] = f2bf((v - mu[w]) * rs[w] * g[c] + bt[c]);
    xc[idx] = f2bf(v);
  }
}

// ---------------- pd (MFMA): per-token 128->20 projection, scatter to pdh/pdw ----------------
__global__ __launch_bounds__(256) void pd_mfma(const unsigned short* __restrict__ ubf,
    const unsigned short* __restrict__ wcatT, const float* __restrict__ hbnd,
    const float* __restrict__ wbnd, unsigned short* __restrict__ pdh,
    unsigned short* __restrict__ pdw) {
  __shared__ __align__(16) unsigned short sU[64 * 128];
  __shared__ __align__(16) unsigned short sW[32 * 128];
  int tid = threadIdx.x;
  int tok0 = blockIdx.x * 64;
  #pragma unroll
  for (int i = 0; i < 4; ++i) {
    int s = i * 256 + tid; int r = s >> 4, c = s & 15;
    u32x4 v = *reinterpret_cast<const u32x4*>(ubf + (size_t)(tok0 + r) * 128 + c * 8);
    *reinterpret_cast<u32x4*>(sU + r * 128 + ((c ^ (r & 7)) * 8)) = v;
  }
  #pragma unroll
  for (int i = 0; i < 2; ++i) {
    int s = i * 256 + tid; int r = s >> 4, c = s & 15;
    u32x4 v = *reinterpret_cast<const u32x4*>(wcatT + (size_t)r * 128 + c * 8);
    *reinterpret_cast<u32x4*>(sW + r * 128 + ((c ^ (r & 7)) * 8)) = v;
  }
  __syncthreads();
  int wid = tid >> 6, lane = tid & 63, l16 = lane & 15, lk = lane >> 4;
  f32x4 acc[2] = {};
  #pragma unroll
  for (int kk = 0; kk < 4; ++kk) {
    bhalf8 a = ldsFrag<16>(sU, wid * 16 + l16, kk * 4 + lk);
    #pragma unroll
    for (int f = 0; f < 2; ++f) {
      bhalf8 b = ldsFrag<16>(sW, f * 16 + l16, kk * 4 + lk);
      acc[f] = MFMA(a, b, acc[f]);
    }
  }
  #pragma unroll
  for (int f = 0; f < 2; ++f) {
    int n = f * 16 + l16;
    #pragma unroll
    for (int r = 0; r < 4; ++r) {
      int tok = tok0 + wid * 16 + lk * 4 + r;
      float v = acc[f][r];
      if (n < 10) {
        pdh[((size_t)(tok / 56)) * NDP + (size_t)(tok % 56) * 10 + n] = f2bf(v + hbnd[n]);
      } else if (n < 20) {
        int b = tok / HWHW; int rem = tok % HWHW; int hh = rem / 56; int w = rem % 56;
        pdw[((size_t)(b * 56 + w)) * NDP + (size_t)hh * 10 + (n - 10)] = f2bf(v + wbnd[n - 10]);
      }
    }
  }
}

// ---------------- merged logits GEMM: both h- and w-direction in one launch ----------------
__global__ __launch_bounds__(256) void gemm_logits(
    const unsigned short* __restrict__ pdh, const unsigned short* __restrict__ pdw,
    const unsigned short* __restrict__ wnnTh, const unsigned short* __restrict__ wnnTw,
    const float* __restrict__ hbnn, const float* __restrict__ wbnn,
    unsigned short* __restrict__ ph, unsigned short* __restrict__ pwb) {
  __shared__ __align__(16) unsigned short sA[128 * 64];
  __shared__ __align__(16) unsigned short sB[128 * 64];
  int tid = threadIdx.x;
  int byr = blockIdx.y;
  const unsigned short* A; const unsigned short* BT; const float* bias; unsigned short* Cout;
  int row0;
  if (byr < 14) { A = pdh; BT = wnnTh; bias = hbnn; Cout = ph;  row0 = byr * 128; }
  else          { A = pdw; BT = wnnTw; bias = wbnn; Cout = pwb; row0 = (byr - 14) * 128; }
  int col0 = blockIdx.x * 128;
  int wid = tid >> 6, lane = tid & 63;
  int wm = wid >> 1, wn = wid & 1;
  int l16 = lane & 15, lk = lane >> 4;
  f32x4 acc[4][4] = {};
  for (int k0 = 0; k0 < NDP; k0 += 64) {
    #pragma unroll
    for (int i = 0; i < 4; ++i) {
      int s = i * 256 + tid; int r = s >> 3, c = s & 7;
      u32x4 v = *reinterpret_cast<const u32x4*>(A + (size_t)(row0 + r) * NDP + k0 + c * 8);
      *reinterpret_cast<u32x4*>(sA + r * 64 + ((c ^ (r & 7)) * 8)) = v;
    }
    #pragma unroll
    for (int i = 0; i < 4; ++i) {
      int s = i * 256 + tid; int r = s >> 3, c = s & 7;
      u32x4 v = *reinterpret_cast<const u32x4*>(BT + (size_t)(col0 + r) * NDP + k0 + c * 8);
      *reinterpret_cast<u32x4*>(sB + r * 64 + ((c ^ (r & 7)) * 8)) = v;
    }
    __syncthreads();
    bhalf8 af[4][2], bf[4][2];
    #pragma unroll
    for (int f = 0; f < 4; ++f)
      #pragma unroll
      for (int kk = 0; kk < 2; ++kk) {
        af[f][kk] = ldsFrag<8>(sA, wm * 64 + f * 16 + l16, kk * 4 + lk);
        bf[f][kk] = ldsFrag<8>(sB, wn * 64 + f * 16 + l16, kk * 4 + lk);
      }
    #pragma unroll
    for (int i = 0; i < 4; ++i)
      #pragma unroll
      for (int j = 0; j < 4; ++j) {
        acc[i][j] = MFMA(af[i][0], bf[j][0], acc[i][j]);
        acc[i][j] = MFMA(af[i][1], bf[j][1], acc[i][j]);
      }
    __syncthreads();
  }
  #pragma unroll
  for (int i = 0; i < 4; ++i) {
    int rbase = row0 + wm * 64 + i * 16 + lk * 4;
    #pragma unroll
    for (int j = 0; j < 4; ++j) {
      int col = col0 + wn * 64 + j * 16 + l16;
      if (col < HWHW) {
        float bv = bias[col];
        #pragma unroll
        for (int r = 0; r < 4; ++r)
          Cout[(size_t)(rbase + r) * NNP + col] = f2bf(acc[i][j][r] + bv);
      }
    }
  }
}

// ---------------- softmax over contiguous groups of 56 (bf16, row stride 3200) ----------------
__global__ __launch_bounds__(256) void softmax56_kernel(unsigned short* __restrict__ ph,
                                                        unsigned short* __restrict__ pw) {
  int wave = (blockIdx.x * 256 + threadIdx.x) >> 6;
  int lane = threadIdx.x & 63;
  if (wave >= 2 * TOK) return;
  unsigned short* buf = wave < TOK ? ph : pw;
  int row = wave < TOK ? wave : wave - TOK;
  int bh = row / 56, i = row % 56;
  unsigned short* p = buf + (size_t)bh * NNP + (size_t)i * 56;
  float xv = lane < WW ? bf2f(p[lane]) : -INFINITY;
  float m = xv;
  for (int o = 32; o > 0; o >>= 1) m = fmaxf(m, __shfl_xor(m, o));
  float e = lane < WW ? __expf(xv - m) : 0.f;
  float s = e;
  for (int o = 32; o > 0; o >>= 1) s += __shfl_xor(s, o);
  if (lane < WW) p[lane] = f2bf(e * __builtin_amdgcn_rcpf(s));
}

// ---------------- mix_h + pc fused: accm = P_h @ U + U @ pc + pc_b  (bf16 out) ----------------
__global__ __launch_bounds__(256) void mixh_pc(const unsigned short* __restrict__ ph,
    const unsigned short* __restrict__ ubf, const unsigned short* __restrict__ pcT,
    const float* __restrict__ pcb, unsigned short* __restrict__ accm) {
  int bh = blockIdx.x;
  int tok0 = bh * 56;
  __shared__ __align__(16) unsigned short sUt[128 * 64];
  int tid = threadIdx.x;
  for (int s = tid; s < 1024; s += 256) {
    int j = s >> 4, cc = s & 15;
    unsigned short e8[8] = {0, 0, 0, 0, 0, 0, 0, 0};
    if (j < 56)
      *reinterpret_cast<u32x4*>(e8) =
          *reinterpret_cast<const u32x4*>(ubf + (size_t)(tok0 + j) * 128 + cc * 8);
    #pragma unroll
    for (int e = 0; e < 8; ++e) {
      int cf = cc * 8 + e;
      sUt[cf * 64 + (((j >> 3) ^ (cf & 7)) * 8) + (j & 7)] = e8[e];
    }
  }
  __syncthreads();
  int lane = tid & 63, l16 = lane & 15, lk = lane >> 4, wn = tid >> 6;
  const unsigned short* prow = ph + (size_t)bh * NNP;
  f32x4 acc[4][2] = {};
  #pragma unroll
  for (int kk = 0; kk < 2; ++kk) {
    bhalf8 a[4], b[2];
    #pragma unroll
    for (int i = 0; i < 4; ++i)
      a[i] = gFrag(prow + (i * 16 + l16) * 56 + (kk * 4 + lk) * 8);
    #pragma unroll
    for (int j = 0; j < 2; ++j) b[j] = ldsFrag<8>(sUt, wn * 32 + j * 16 + l16, kk * 4 + lk);
    #pragma unroll
    for (int i = 0; i < 4; ++i)
      #pragma unroll
      for (int j = 0; j < 2; ++j) acc[i][j] = MFMA(a[i], b[j], acc[i][j]);
  }
  #pragma unroll
  for (int kk = 0; kk < 4; ++kk) {
    bhalf8 a[4], b[2];
    #pragma unroll
    for (int i = 0; i < 4; ++i)
      a[i] = gFrag(ubf + (size_t)(tok0 + i * 16 + l16) * 128 + (kk * 4 + lk) * 8);
    #pragma unroll
    for (int j = 0; j < 2; ++j)
      b[j] = gFrag(pcT + (size_t)(wn * 32 + j * 16 + l16) * 128 + (kk * 4 + lk) * 8);
    #pragma unroll
    for (int i = 0; i < 4; ++i)
      #pragma unroll
      for (int j = 0; j < 2; ++j) acc[i][j] = MFMA(a[i], b[j], acc[i][j]);
  }
  #pragma unroll
  for (int i = 0; i < 4; ++i) {
    int tok = i * 16 + lk * 4;
    #pragma unroll
    for (int j = 0; j < 2; ++j) {
      int c = wn * 32 + j * 16 + l16;
      float bv = pcb[c];
      #pragma unroll
      for (int r = 0; r < 4; ++r)
        if (tok + r < 56)
          accm[(size_t)(tok0 + tok + r) * 128 + c] = f2bf(acc[i][j][r] + bv);
    }
  }
}

// ---------------- mix_w + po + residual + LN2 fused ----------------
__global__ __launch_bounds__(256) void mixw_fin(const unsigned short* __restrict__ pw,
    const unsigned short* __restrict__ ubf, const unsigned short* __restrict__ poT,
    const float* __restrict__ pob, const unsigned short* __restrict__ xcl,
    unsigned short* __restrict__ accXt,
    const float* __restrict__ ln2g, const float* __restrict__ ln2b,
    unsigned short* __restrict__ vbf) {
  int bw = blockIdx.x;
  int bq = bw / 56, w = bw % 56;
  __shared__ __align__(16) unsigned short sUt[128 * 64];
  __shared__ __align__(16) unsigned short sS[64 * 128];
  int tid = threadIdx.x;
  for (int s = tid; s < 1024; s += 256) {
    int j = s >> 4, cc = s & 15;
    unsigned short e8[8] = {0, 0, 0, 0, 0, 0, 0, 0};
    if (j < 56)
      *reinterpret_cast<u32x4*>(e8) =
          *reinterpret_cast<const u32x4*>(ubf + ((size_t)bq * HWHW + (size_t)j * 56 + w) * 128 + cc * 8);
    #pragma unroll
    for (int e = 0; e < 8; ++e) {
      int cf = cc * 8 + e;
      sUt[cf * 64 + (((j >> 3) ^ (cf & 7)) * 8) + (j & 7)] = e8[e];
    }
  }
  for (int s = tid; s < 1024; s += 256) {
    int r = s >> 4, c = s & 15;
    u32x4 v = {0, 0, 0, 0};
    if (r < 56) v = *reinterpret_cast<const u32x4*>(accXt + ((size_t)bq * HWHW + (size_t)r * 56 + w) * 128 + c * 8);
    *reinterpret_cast<u32x4*>(sS + r * 128 + ((c ^ (r & 7)) * 8)) = v;
  }
  __syncthreads();
  int lane = tid & 63, l16 = lane & 15, lk = lane >> 4, wn = tid >> 6;
  const unsigned short* prow = pw + (size_t)bw * NNP;
  f32x4 acc1[4][2] = {};
  #pragma unroll
  for (int kk = 0; kk < 2; ++kk) {
    bhalf8 a[4], b[2];
    #pragma unroll
    for (int i = 0; i < 4; ++i)
      a[i] = gFrag(prow + (i * 16 + l16) * 56 + (kk * 4 + lk) * 8);
    #pragma unroll
    for (int j = 0; j < 2; ++j) b[j] = ldsFrag<8>(sUt, wn * 32 + j * 16 + l16, kk * 4 + lk);
    #pragma unroll
    for (int i = 0; i < 4; ++i)
      #pragma unroll
      for (int j = 0; j < 2; ++j) acc1[i][j] = MFMA(a[i], b[j], acc1[i][j]);
  }
  __syncthreads();
  // sS = accm_tile + yw  (RMW by owner lanes; pad rows stay zero)
  #pragma unroll
  for (int i = 0; i < 4; ++i) {
    #pragma unroll
    for (int j = 0; j < 2; ++j) {
      int col = wn * 32 + j * 16 + l16;
      #pragma unroll
      for (int r = 0; r < 4; ++r) {
        int row = i * 16 + lk * 4 + r;
        int ad = row * 128 + (((col >> 3) ^ (row & 7)) * 8) + (col & 7);
        sS[ad] = f2bf(bf2f(sS[ad]) + acc1[i][j][r]);
      }
    }
  }
  __syncthreads();
  f32x4 acc2[4][2] = {};
  #pragma unroll
  for (int kk = 0; kk < 4; ++kk) {
    bhalf8 a[4], b[2];
    #pragma unroll
    for (int i = 0; i < 4; ++i) a[i] = ldsFrag<16>(sS, i * 16 + l16, kk * 4 + lk);
    #pragma unroll
    for (int j = 0; j < 2; ++j)
      b[j] = gFrag(poT + (size_t)(wn * 32 + j * 16 + l16) * 128 + (kk * 4 + lk) * 8);
    #pragma unroll
    for (int i = 0; i < 4; ++i)
      #pragma unroll
      for (int j = 0; j < 2; ++j) acc2[i][j] = MFMA(a[i], b[j], acc2[i][j]);
  }
  __syncthreads();   // all A-frag reads of sS done before overwrite below
  #pragma unroll
  for (int i = 0; i < 4; ++i) {
    #pragma unroll
    for (int j = 0; j < 2; ++j) {
      int c = wn * 32 + j * 16 + l16;
      float bv = pob[c];
      #pragma unroll
      for (int r = 0; r < 4; ++r) {
        int row = i * 16 + lk * 4 + r;
        if (row < 56) {
          size_t t = (size_t)bq * HWHW + (size_t)row * 56 + w;
          float z = acc2[i][j][r] + bv + bf2f(xcl[t * 128 + c]);
          unsigned short zb = f2bf(z);
          accXt[t * 128 + c] = zb;
          sS[row * 128 + (((c >> 3) ^ (row & 7)) * 8) + (c & 7)] = zb;  // for LN phase
        }
      }
    }
  }
  __syncthreads();
  // LN2 phase: wave per row (56 rows), 2 channels per lane
  {
    int wid4 = tid >> 6;
    int c0 = 2 * lane;
    float g0 = ln2g[c0], g1 = ln2g[c0 + 1];
    float b0 = ln2b[c0], b1 = ln2b[c0 + 1];
    for (int row = wid4; row < 56; row += 4) {
      int ad = row * 128 + (((c0 >> 3) ^ (row & 7)) * 8) + (c0 & 7);
      unsigned int wrd = *reinterpret_cast<const unsigned int*>(sS + ad);
      float z0 = bf2f((unsigned short)(wrd & 0xFFFFu));
      float z1 = bf2f((unsigned short)(wrd >> 16));
      float s1 = z0 + z1, s2 = z0 * z0 + z1 * z1;
      for (int o = 32; o > 0; o >>= 1) { s1 += __shfl_xor(s1, o); s2 += __shfl_xor(s2, o); }
      float m = s1 * (1.0f / CC);
      float var = s2 * (1.0f / CC) - m * m;
      float rv = rsqrtf(var + 1e-5f);
      float n0 = (z0 - m) * rv * g0 + b0;
      float n1 = (z1 - m) * rv * g1 + b1;
      size_t t = (size_t)bq * HWHW + (size_t)row * 56 + w;
      *reinterpret_cast<unsigned int*>(vbf + t * 128 + c0) = pack2(n0, n1);
    }
  }
}

// ---------------- fc1 GEMM: h[tok][hid] = gelu(vbf @ fc1 + b1), K=128 ----------------
// XCD-chunked 1D grid: 3136 = 8 XCD x 98 tok-chunks x 4 hid; the 4 hid-blocks of a
// token tile are consecutive on the SAME XCD -> its private L2 serves 3 of 4 vbf reads.
__global__ __launch_bounds__(256) void gemm_fc1(const unsigned short* __restrict__ vbf,
    const unsigned short* __restrict__ fc1T, const float* __restrict__ b1,
    unsigned short* __restrict__ hbuf) {
  __shared__ __align__(16) unsigned short sW[128 * 64];
  __shared__ __align__(16) unsigned short sV[128 * 64];
  __shared__ float b1s[128];
  int tid = threadIdx.x;
  int id = blockIdx.x;
  int xcd = id & 7, sub = id >> 3;
  int tok0 = (xcd * 98 + (sub >> 2)) * 128;
  int hidT = (sub & 3) * 128;
  if (tid < 128) b1s[tid] = b1[hidT + tid];
  int wid = tid >> 6, lane = tid & 63;
  int wm = wid >> 1, wn = wid & 1;      // wm: hid half, wn: tok half
  int l16 = lane & 15, lk = lane >> 4;
  f32x4 acc[4][4] = {};
  for (int k0 = 0; k0 < 128; k0 += 64) {
    #pragma unroll
    for (int i = 0; i < 4; ++i) {
      int s = i * 256 + tid; int r = s >> 3, c = s & 7;
      u32x4 v = *reinterpret_cast<const u32x4*>(fc1T + (size_t)(hidT + r) * 128 + k0 + c * 8);
      *reinterpret_cast<u32x4*>(sW + r * 64 + ((c ^ (r & 7)) * 8)) = v;
    }
    #pragma unroll
    for (int i = 0; i < 4; ++i) {
      int s = i * 256 + tid; int r = s >> 3, c = s & 7;
      u32x4 v = *reinterpret_cast<const u32x4*>(vbf + (size_t)(tok0 + r) * 128 + k0 + c * 8);
      *reinterpret_cast<u32x4*>(sV + r * 64 + ((c ^ (r & 7)) * 8)) = v;
    }
    __syncthreads();
    bhalf8 af[4][2], bf[4][2];
    #pragma unroll
    for (int f = 0; f < 4; ++f)
      #pragma unroll
      for (int kk = 0; kk < 2; ++kk) {
        af[f][kk] = ldsFrag<8>(sW, wm * 64 + f * 16 + l16, kk * 4 + lk);
        bf[f][kk] = ldsFrag<8>(sV, wn * 64 + f * 16 + l16, kk * 4 + lk);
      }
    #pragma unroll
    for (int i = 0; i < 4; ++i)
      #pragma unroll
      for (int j = 0; j < 4; ++j) {
        acc[i][j] = MFMA(af[i][0], bf[j][0], acc[i][j]);
        acc[i][j] = MFMA(af[i][1], bf[j][1], acc[i][j]);
      }
    __syncthreads();
  }
  #pragma unroll
  for (int i = 0; i < 4; ++i) {
    int hidL = wm * 64 + i * 16 + lk * 4;
    #pragma unroll
    for (int j = 0; j < 4; ++j) {
      int tokL = wn * 64 + j * 16 + l16;
      float v0 = gelu_f(acc[i][j][0] + b1s[hidL]);
      float v1 = gelu_f(acc[i][j][1] + b1s[hidL + 1]);
      float v2 = gelu_f(acc[i][j][2] + b1s[hidL + 2]);
      float v3 = gelu_f(acc[i][j][3] + b1s[hidL + 3]);
      unsigned long long pk = (unsigned long long)pack2(v0, v1)
                            | ((unsigned long long)pack2(v2, v3) << 32);
      *reinterpret_cast<unsigned long long*>(
          hbuf + (size_t)(tok0 + tokL) * 512 + hidT + hidL) = pk;
    }
  }
}

// ---------------- fc2 GEMM: out = T(xt2 + h @ fc2 + b2), K=512 ----------------
__global__ __launch_bounds__(256) void gemm_fc2(const unsigned short* __restrict__ hbuf,
    const unsigned short* __restrict__ fc2T, const float* __restrict__ b2,
    const unsigned short* __restrict__ xt2, float* __restrict__ out) {
  __shared__ __align__(16) unsigned short smem[2][128 * 64];   // sH / sC, reused as xtile
  __shared__ float b2s[128];
  unsigned short* sH = smem[0];
  unsigned short* sC = smem[1];
  unsigned short* xtile = &smem[0][0];   // 128x128 bf16 = 32KB (both halves)
  int tid = threadIdx.x;
  int tok0 = blockIdx.x * 128;
  if (tid < 128) b2s[tid] = b2[tid];
  int wid = tid >> 6, lane = tid & 63;
  int wm = wid >> 1, wn = wid & 1;       // wm: tok half, wn: c half
  int l16 = lane & 15, lk = lane >> 4;
  f32x4 acc[4][4] = {};
  for (int k0 = 0; k0 < 512; k0 += 64) {
    #pragma unroll
    for (int i = 0; i < 4; ++i) {
      int s = i * 256 + tid; int r = s >> 3, c = s & 7;
      u32x4 v = *reinterpret_cast<const u32x4*>(hbuf + (size_t)(tok0 + r) * 512 + k0 + c * 8);
      *reinterpret_cast<u32x4*>(sH + r * 64 + ((c ^ (r & 7)) * 8)) = v;
    }
    #pragma unroll
    for (int i = 0; i < 4; ++i) {
      int s = i * 256 + tid; int r = s >> 3, c = s & 7;
      u32x4 v = *reinterpret_cast<const u32x4*>(fc2T + (size_t)r * 512 + k0 + c * 8);
      *reinterpret_cast<u32x4*>(sC + r * 64 + ((c ^ (r & 7)) * 8)) = v;
    }
    __syncthreads();
    bhalf8 af[4][2], bf[4][2];
    #pragma unroll
    for (int f = 0; f < 4; ++f)
      #pragma unroll
      for (int kk = 0; kk < 2; ++kk) {
        af[f][kk] = ldsFrag<8>(sH, wm * 64 + f * 16 + l16, kk * 4 + lk);
        bf[f][kk] = ldsFrag<8>(sC, wn * 64 + f * 16 + l16, kk * 4 + lk);
      }
    #pragma unroll
    for (int i = 0; i < 4; ++i)
      #pragma unroll
      for (int j = 0; j < 4; ++j) {
        acc[i][j] = MFMA(af[i][0], bf[j][0], acc[i][j]);
        acc[i][j] = MFMA(af[i][1], bf[j][1], acc[i][j]);
      }
    __syncthreads();
  }
  // stage xt2 tile [128 tok][128 c] into LDS (linear), then epilogue
  #pragma unroll
  for (int i = 0; i < 8; ++i) {
    int s = i * 256 + tid; int r = s >> 4, c = s & 15;
    u32x4 v = *reinterpret_cast<const u32x4*>(xt2 + (size_t)(tok0 + r) * 128 + c * 8);
    *reinterpret_cast<u32x4*>(xtile + r * 128 + c * 8) = v;
  }
  __syncthreads();
  #pragma unroll
  for (int i = 0; i < 4; ++i) {
    int tokL = wm * 64 + i * 16 + lk * 4;
    int tokG = tok0 + tokL;
    int bqv = tokG / HWHW;
    int pos = tokG - bqv * HWHW;
    #pragma unroll
    for (int j = 0; j < 4; ++j) {
      int cL = wn * 64 + j * 16 + l16;
      float bv = b2s[cL];
      f32x4 o;
      #pragma unroll
      for (int r = 0; r < 4; ++r)
        o[r] = acc[i][j][r] + bv + bf2f(xtile[(tokL + r) * 128 + cL]);
      *reinterpret_cast<f32x4*>(out + ((size_t)(bqv * CC + cL)) * HWHW + pos) = o;
    }
  }
}

extern "C" void kernel_launch(void* const* d_in, const int* in_sizes, int n_in,
                              void* d_out, int out_size, void* d_ws, size_t ws_size,
                              hipStream_t stream) {
  const float* x     = (const float*)d_in[0];
  const float* ln1_g = (const float*)d_in[1];
  const float* ln1_b = (const float*)d_in[2];
  const float* h_wnd = (const float*)d_in[3];
  const float* h_bnd = (const float*)d_in[4];
  const float* h_wnn = (const float*)d_in[5];
  const float* h_bnn = (const float*)d_in[6];
  const float* w_wnd = (const float*)d_in[7];
  const float* w_bnd = (const float*)d_in[8];
  const float* w_wnn = (const float*)d_in[9];
  const float* w_bnn = (const float*)d_in[10];
  const float* pc_w  = (const float*)d_in[11];
  const float* pc_b  = (const float*)d_in[12];
  const float* po_w  = (const float*)d_in[13];
  const float* po_b  = (const float*)d_in[14];
  const float* ln2_g = (const float*)d_in[15];
  const float* ln2_b = (const float*)d_in[16];
  const float* fc1_w = (const float*)d_in[17];
  const float* fc1_b = (const float*)d_in[18];
  const float* fc2_w = (const float*)d_in[19];
  const float* fc2_b = (const float*)d_in[20];
  float* out = (float*)d_out;
  char* ws = (char*)d_ws;

  // ---- workspace layout (bytes), total ~180.2 MB (ws = 256 MiB per harness poison size) ----
  unsigned short* ubf   = (unsigned short*)(ws + 0);            // 25,690,112 (u; later vbf in-place)
  unsigned short* xcl   = (unsigned short*)(ws + 25690112);     // 25,690,112
  unsigned short* accXt = (unsigned short*)(ws + 51380224);     // 25,690,112 (accm then xt2)
  // region 77,070,336..179,830,784: early buffers; later hbuf (full, 102,760,448)
  unsigned short* pdh   = (unsigned short*)(ws + 77070336);     //  2,064,384
  unsigned short* pdw   = (unsigned short*)(ws + 79134720);     //  2,064,384
  unsigned short* ph    = (unsigned short*)(ws + 81199104);     // 11,468,800
  unsigned short* pw    = (unsigned short*)(ws + 92667904);     // 11,468,800
  unsigned short* wnnTh = (unsigned short*)(ws + 104136704);    //  3,686,400
  unsigned short* wnnTw = (unsigned short*)(ws + 107823104);    //  3,686,400
  unsigned short* hbuf  = (unsigned short*)(ws + 77070336);     // 102,760,448 (after mixes)
  unsigned short* pcT   = (unsigned short*)(ws + 179830784);    //     32,768
  unsigned short* poT   = (unsigned short*)(ws + 179863552);    //     32,768
  unsigned short* fc1T  = (unsigned short*)(ws + 179896320);    //    131,072
  unsigned short* fc2T  = (unsigned short*)(ws + 180027392);    //    131,072
  unsigned short* wcatT = (unsigned short*)(ws + 180158464);    //      8,192
  unsigned short* vbf   = ubf;                                  // reuse (u dead after mixw_fin)

  wtrans_kernel<<<1004, 256, 0, stream>>>(h_wnn, w_wnn, pc_w, po_w, fc1_w, fc2_w,
      h_wnd, w_wnd, wnnTh, wnnTw, pcT, poT, fc1T, fc2T, wcatT, (u32x4*)pdh);
  ln1_kernel<<<BH, 256, 0, stream>>>(x, ln1_g, ln1_b, ubf, xcl);
  pd_mfma<<<TOK / 64, 256, 0, stream>>>(ubf, wcatT, h_bnd, w_bnd, pdh, pdw);
  gemm_logits<<<dim3(NNP / 128, 28), 256, 0, stream>>>(pdh, pdw, wnnTh, wnnTw,
      h_bnn, w_bnn, ph, pw);
  softmax56_kernel<<<(2 * TOK) / 4, 256, 0, stream>>>(ph, pw);
  mixh_pc<<<BH, 256, 0, stream>>>(ph, ubf, pcT, pc_b, accXt);
  mixw_fin<<<BB * WW, 256, 0, stream>>>(pw, ubf, poT, po_b, xcl, accXt,
      ln2_g, ln2_b, vbf);
  gemm_fc1<<<3136, 256, 0, stream>>>(vbf, fc1T, fc1_b, hbuf);
  gemm_fc2<<<TOK / 128, 256, 0, stream>>>(hbuf, fc2T, fc2_b, accXt, out);
}